// Round 6
// baseline (192.950 us; speedup 1.0000x reference)
//
#include <hip/hip_runtime.h>
#include <hip/hip_bf16.h>

// SAGAN self-attention, B=16, C=128, H=W=64. Inputs fp32, output fp32.
// ws layout in ushorts (bf16):
//   U_WN  = 0        : Wn bf16 [96][128] (theta 0..15, phi 16..31, g 32..95)
//   U_WO  = 12288    : Wo bf16 [128][64]
//   U_TH  = 20480    : thetaT bf16 [16 b][4096 s][16 c]
//   U_PHI = 1069056  : phiT   bf16 [16 b][1024 t][16 c]
//   U_G   = 1331200  : g      bf16 [16 b][64 c][1024 t]
//   U_OT  = 2379776  : oT     bf16 [16 b][4096 s][64 c]

#define U_WN  0
#define U_WO  12288
#define U_TH  20480
#define U_PHI 1069056
#define U_G   1331200
#define U_OT  2379776

typedef __attribute__((ext_vector_type(8)))  short bf16x8;
typedef __attribute__((ext_vector_type(4)))  short s16x4;
typedef __attribute__((ext_vector_type(4)))  float f32x4;
typedef __attribute__((ext_vector_type(16))) float f32x16;

__device__ inline unsigned short f2b(float f) {
    union { float f; unsigned u; } v; v.f = f;
    unsigned r = v.u + 0x7FFFu + ((v.u >> 16) & 1u);   // RNE
    return (unsigned short)(r >> 16);
}
__device__ inline unsigned short f2b_trunc(float f) {
    union { float f; unsigned u; } v; v.f = f;
    return (unsigned short)(v.u >> 16);                // RTZ: 1 instr, ok for P
}
__device__ inline float b2f(unsigned short u) {
    union { unsigned u; float f; } v; v.u = ((unsigned)u) << 16; return v.f;
}

// ---------------- Kernel A: spectral norm, emit bf16 weights ----------------
__global__ __launch_bounds__(256) void sn4(
        const float* __restrict__ w0, const float* __restrict__ w1,
        const float* __restrict__ w2, const float* __restrict__ w3,
        const float* __restrict__ u0, const float* __restrict__ u1,
        const float* __restrict__ u2, const float* __restrict__ u3,
        unsigned short* __restrict__ wsu) {
    int wi = blockIdx.x;
    const float* W; const float* u; unsigned short* dst; int on, in_;
    if      (wi == 0) { W = w0; u = u0; dst = wsu;          on = 16;  in_ = 128; }
    else if (wi == 1) { W = w1; u = u1; dst = wsu + 2048;   on = 16;  in_ = 128; }
    else if (wi == 2) { W = w2; u = u2; dst = wsu + 4096;   on = 64;  in_ = 128; }
    else              { W = w3; u = u3; dst = wsu + 12288;  on = 128; in_ = 64;  }
    __shared__ float Wl[8320];    // [on][in_+1]
    __shared__ float ul[128];
    __shared__ float v[128];
    __shared__ float red[256];
    __shared__ float s_inv;
    int tid = threadIdx.x;
    int n = on * in_;
    int stride = in_ + 1;
    int shift = (in_ == 128) ? 7 : 6;
    int mask = in_ - 1;
    for (int i = tid; i < n; i += 256) {
        int o = i >> shift, j = i & mask;
        Wl[o * stride + j] = W[i];
    }
    if (tid < on) ul[tid] = u[tid];
    __syncthreads();
    float vi = 0.f;
    if (tid < in_) {
        for (int o = 0; o < on; ++o) vi += ul[o] * Wl[o * stride + tid];
    }
    red[tid] = (tid < in_) ? vi * vi : 0.f;
    __syncthreads();
    for (int st = 128; st > 0; st >>= 1) {
        if (tid < st) red[tid] += red[tid + st];
        __syncthreads();
    }
    float inv_nv = 1.0f / fmaxf(sqrtf(red[0]), 1e-12f);
    __syncthreads();
    if (tid < in_) v[tid] = vi * inv_nv;
    __syncthreads();
    float ui = 0.f;
    if (tid < on) {
        for (int i = 0; i < in_; ++i) ui += v[i] * Wl[tid * stride + i];
    }
    red[tid] = (tid < on) ? ui * ui : 0.f;
    __syncthreads();
    for (int st = 128; st > 0; st >>= 1) {
        if (tid < st) red[tid] += red[tid + st];
        __syncthreads();
    }
    if (tid == 0) {
        float nsq = red[0];
        float sv = nsq / fmaxf(sqrtf(nsq), 1e-12f);
        s_inv = 1.0f / sv;
    }
    __syncthreads();
    float inv = s_inv;
    for (int e = tid; e < n; e += 256) {
        int o = e >> shift, j = e & mask;
        dst[e] = f2b(Wl[o * stride + j] * inv);
    }
}

// ------- Kernel B: MFMA conv + 2x2 maxpool (unchanged this round) -----------
__global__ __launch_bounds__(256) void convpool_mfma(
        const float* __restrict__ x, const unsigned short* __restrict__ wn,
        unsigned short* __restrict__ thetaT, unsigned short* __restrict__ phiT,
        unsigned short* __restrict__ gT) {
    __shared__ unsigned short smem[128 * 136];   // xT [px][c] s136; later poolbuf [80][132]
    int tid = threadIdx.x;
    int bb = blockIdx.x >> 5, tile = blockIdx.x & 31;
    int px0 = tile << 7;
    const float4* x4 = (const float4*)x;
    {
        int p4 = tid & 31, cg = (tid >> 5) * 4;
        for (int k = 0; k < 4; ++k) {
            int cb = k * 32 + cg;
            float4 v0 = x4[(bb * 128 + cb + 0) * 1024 + tile * 32 + p4];
            float4 v1 = x4[(bb * 128 + cb + 1) * 1024 + tile * 32 + p4];
            float4 v2 = x4[(bb * 128 + cb + 2) * 1024 + tile * 32 + p4];
            float4 v3 = x4[(bb * 128 + cb + 3) * 1024 + tile * 32 + p4];
            float a0[4] = {v0.x, v0.y, v0.z, v0.w};
            float a1[4] = {v1.x, v1.y, v1.z, v1.w};
            float a2[4] = {v2.x, v2.y, v2.z, v2.w};
            float a3[4] = {v3.x, v3.y, v3.z, v3.w};
#pragma unroll
            for (int j = 0; j < 4; ++j) {
                s16x4 u; u[0] = (short)f2b(a0[j]); u[1] = (short)f2b(a1[j]);
                u[2] = (short)f2b(a2[j]); u[3] = (short)f2b(a3[j]);
                *(s16x4*)&smem[(p4 * 4 + j) * 136 + cb] = u;
            }
        }
    }
    __syncthreads();
    int lane = tid & 63, wv = tid >> 6;
    int q = lane >> 4, l = lane & 15;
    int pxw = wv * 32;
    f32x4 acc[2][6];
    const f32x4 z4 = {0.f, 0.f, 0.f, 0.f};
#pragma unroll
    for (int mt = 0; mt < 2; ++mt)
#pragma unroll
        for (int nt = 0; nt < 6; ++nt) acc[mt][nt] = z4;
#pragma unroll
    for (int kk = 0; kk < 4; ++kk) {
        bf16x8 a0 = *(const bf16x8*)&smem[(pxw + l) * 136 + kk * 32 + q * 8];
        bf16x8 a1 = *(const bf16x8*)&smem[(pxw + 16 + l) * 136 + kk * 32 + q * 8];
#pragma unroll
        for (int nt = 0; nt < 6; ++nt) {
            bf16x8 bw = *(const bf16x8*)&wn[(nt * 16 + l) * 128 + kk * 32 + q * 8];
            acc[0][nt] = __builtin_amdgcn_mfma_f32_16x16x32_bf16(a0, bw, acc[0][nt], 0, 0, 0);
            acc[1][nt] = __builtin_amdgcn_mfma_f32_16x16x32_bf16(a1, bw, acc[1][nt], 0, 0, 0);
        }
    }
#pragma unroll
    for (int mt = 0; mt < 2; ++mt)
#pragma unroll
        for (int r = 0; r < 4; ++r) {
            int s = px0 + pxw + mt * 16 + q * 4 + r;
            thetaT[(bb * 4096 + s) * 16 + l] = f2b(acc[mt][0][r]);
        }
    __syncthreads();
    unsigned short* poolbuf = smem;   // [80 ch][px] stride 132
#pragma unroll
    for (int mt = 0; mt < 2; ++mt)
#pragma unroll
        for (int nt = 1; nt < 6; ++nt) {
            int ch = nt * 16 + l - 16;
#pragma unroll
            for (int r = 0; r < 4; ++r) {
                poolbuf[ch * 132 + pxw + mt * 16 + q * 4 + r] = f2b(acc[mt][nt][r]);
            }
        }
    __syncthreads();
    for (int i = tid; i < 2560; i += 256) {
        int tcol = i & 31, ch = i >> 5;
        int base = ch * 132 + tcol * 2;
        float m0 = fmaxf(b2f(poolbuf[base]), b2f(poolbuf[base + 1]));
        float m1 = fmaxf(b2f(poolbuf[base + 64]), b2f(poolbuf[base + 65]));
        float m = fmaxf(m0, m1);
        int t = tile * 32 + tcol;
        if (ch < 16) phiT[(bb * 1024 + t) * 16 + ch] = f2b(m);
        else         gT[(bb * 64 + ch - 16) * 1024 + t] = f2b(m);
    }
}

// ------- Kernel C: MFMA fused attention, t-split + dbuf psT -----------------
// grid: 16 b x 64 s-tiles (64 s) = 1024 blocks (4/CU), 4 waves.
// Wave (pair, half): pair = s-subtile (32 s), half = t-range (512 t, 8 chunks).
// 32x32x16 mfma, exact K=16 for S. phi/g frags direct from global (L2-hot).
// psT double-buffered per wave -> no loop-carried LDS hazard, zero in-loop
// barriers. Partial O/L combined across the wave pair via LDS at the end.
__global__ __launch_bounds__(256) void attn_mfma(
        const unsigned short* __restrict__ thetaT,
        const unsigned short* __restrict__ phiT,
        const unsigned short* __restrict__ gT,
        unsigned short* __restrict__ oT) {
    __shared__ unsigned short ldsu[18432];   // 8 psT regions [32 s][72]; overlay comb
    int tid = threadIdx.x;
    int bb = blockIdx.x >> 6, st = blockIdx.x & 63;
    int s0 = st << 6;
    int lane = tid & 63, wv = tid >> 6;
    int m = lane & 31, h = lane >> 5;
    int pair = wv >> 1, half = wv & 1;
    int sW = s0 + pair * 32;
    const f32x16 z16 = {0.f,0.f,0.f,0.f,0.f,0.f,0.f,0.f,0.f,0.f,0.f,0.f,0.f,0.f,0.f,0.f};

    // theta A-frag: A[m=s][k=c], K=16 exact
    bf16x8 a_th = *(const bf16x8*)&thetaT[(bb * 4096 + sW + m) * 16 + h * 8];

    f32x16 acc[2];
    acc[0] = z16; acc[1] = z16;
    float lp[16];
#pragma unroll
    for (int r = 0; r < 16; ++r) lp[r] = 0.f;

    const unsigned short* phB = &phiT[bb * 16384];
    const unsigned short* gB  = &gT[bb * 65536];
    int tbase = half * 512;

    bf16x8 bp[2], bpn[2];
#pragma unroll
    for (int tg = 0; tg < 2; ++tg)
        bp[tg] = *(const bf16x8*)&phB[(tbase + tg * 32 + m) * 16 + h * 8];

#pragma unroll
    for (int i = 0; i < 8; ++i) {
        int t0 = tbase + (i << 6);
        if (i < 7) {   // prefetch next chunk's phi frags
#pragma unroll
            for (int tg = 0; tg < 2; ++tg)
                bpn[tg] = *(const bf16x8*)&phB[(t0 + 64 + tg * 32 + m) * 16 + h * 8];
        }
        unsigned short* ps = &ldsu[(wv * 2 + (i & 1)) * 32 * 72];
        // S = theta^T phi : 32 s x 64 t
        f32x16 sacc0 = __builtin_amdgcn_mfma_f32_32x32x16_bf16(a_th, bp[0], z16, 0, 0, 0);
        f32x16 sacc1 = __builtin_amdgcn_mfma_f32_32x32x16_bf16(a_th, bp[1], z16, 0, 0, 0);
        // P = exp(S) -> ps (wave-private, double-buffered)
#pragma unroll
        for (int r = 0; r < 16; ++r) {
            int row = (r & 3) + 8 * (r >> 2) + 4 * h;
            float e0 = __expf(sacc0[r]);
            float e1 = __expf(sacc1[r]);
            lp[r] += e0 + e1;
            ps[row * 72 + m] = f2b_trunc(e0);
            ps[row * 72 + 32 + m] = f2b_trunc(e1);
        }
        // PV: O^T[s][c] += P[s][t] g^T[t][c]
#pragma unroll
        for (int kt = 0; kt < 4; ++kt) {
            bf16x8 ap = *(const bf16x8*)&ps[m * 72 + kt * 16 + h * 8];
#pragma unroll
            for (int cg = 0; cg < 2; ++cg) {
                bf16x8 bg = *(const bf16x8*)&gB[(cg * 32 + m) * 1024 + t0 + kt * 16 + h * 8];
                acc[cg] = __builtin_amdgcn_mfma_f32_32x32x16_bf16(ap, bg, acc[cg], 0, 0, 0);
            }
        }
        bp[0] = bpn[0]; bp[1] = bpn[1];
    }
    // partial row sums over this wave's 512 t (butterfly within 32-lane h-group)
    float lsum[16];
#pragma unroll
    for (int r = 0; r < 16; ++r) {
        float v = lp[r];
        v += __shfl_xor(v, 1);
        v += __shfl_xor(v, 2);
        v += __shfl_xor(v, 4);
        v += __shfl_xor(v, 8);
        v += __shfl_xor(v, 16);
        lsum[r] = v;
    }
    // combine the two t-halves of each pair through LDS (overlay psT region)
    __syncthreads();                         // all waves done with psT
    float* comb = (float*)ldsu;              // [2 pairs][32 s][64 c] = 16 KB
    float* Lb = (float*)(ldsu + 8192);       // byte 16384: [2 pairs][32 s]
    if (half == 1) {
#pragma unroll
        for (int cg = 0; cg < 2; ++cg)
#pragma unroll
            for (int r = 0; r < 16; ++r) {
                int row = (r & 3) + 8 * (r >> 2) + 4 * h;
                comb[pair * 2048 + row * 64 + cg * 32 + m] = acc[cg][r];
            }
        if (m == 0) {
#pragma unroll
            for (int r = 0; r < 16; ++r) {
                int row = (r & 3) + 8 * (r >> 2) + 4 * h;
                Lb[pair * 32 + row] = lsum[r];
            }
        }
    }
    __syncthreads();
    if (half == 0) {
#pragma unroll
        for (int r = 0; r < 16; ++r) {
            int row = (r & 3) + 8 * (r >> 2) + 4 * h;
            float inv = 1.0f / (lsum[r] + Lb[pair * 32 + row]);
#pragma unroll
            for (int cg = 0; cg < 2; ++cg) {
                float v = acc[cg][r] + comb[pair * 2048 + row * 64 + cg * 32 + m];
                oT[(bb * 4096 + sW + row) * 64 + cg * 32 + m] = f2b(v * inv);
            }
        }
    }
}

// ------- Kernel D: out = gamma * (Wo @ o) + x  (unchanged this round) -------
__global__ __launch_bounds__(256) void outconv_mfma(
        const unsigned short* __restrict__ oT, const unsigned short* __restrict__ wo,
        const float* __restrict__ x, const float* __restrict__ gam,
        float* __restrict__ out) {
    int tid = threadIdx.x;
    int bb = blockIdx.x >> 6, tile = blockIdx.x & 63;
    int lane = tid & 63, wv = tid >> 6;
    int q = lane >> 4, l = lane & 15;
    int pxw = tile * 64 + wv * 16;
    bf16x8 af[2];
#pragma unroll
    for (int kk = 0; kk < 2; ++kk)
        af[kk] = *(const bf16x8*)&oT[(bb * 4096 + pxw + l) * 64 + kk * 32 + q * 8];
    f32x4 acc[8];
    const f32x4 z4 = {0.f, 0.f, 0.f, 0.f};
#pragma unroll
    for (int nt = 0; nt < 8; ++nt) acc[nt] = z4;
#pragma unroll
    for (int kk = 0; kk < 2; ++kk)
#pragma unroll
        for (int nt = 0; nt < 8; ++nt) {
            bf16x8 bw = *(const bf16x8*)&wo[(nt * 16 + l) * 64 + kk * 32 + q * 8];
            acc[nt] = __builtin_amdgcn_mfma_f32_16x16x32_bf16(af[kk], bw, acc[nt], 0, 0, 0);
        }
    float gm = gam[0];
    const float4* x4 = (const float4*)x;
    float4* out4 = (float4*)out;
#pragma unroll
    for (int nt = 0; nt < 8; ++nt) {
        int oc = nt * 16 + l;
        int gi = (bb * 128 + oc) * 1024 + (pxw >> 2) + q;
        float4 xv = x4[gi];
        float4 r;
        r.x = gm * acc[nt][0] + xv.x;
        r.y = gm * acc[nt][1] + xv.y;
        r.z = gm * acc[nt][2] + xv.z;
        r.w = gm * acc[nt][3] + xv.w;
        out4[gi] = r;
    }
}

extern "C" void kernel_launch(void* const* d_in, const int* in_sizes, int n_in,
                              void* d_out, int out_size, void* d_ws, size_t ws_size,
                              hipStream_t stream) {
    const float* x  = (const float*)d_in[0];
    const float* wt = (const float*)d_in[1];
    const float* wp = (const float*)d_in[2];
    const float* wg = (const float*)d_in[3];
    const float* wo = (const float*)d_in[4];
    const float* ut = (const float*)d_in[5];
    const float* up = (const float*)d_in[6];
    const float* ug = (const float*)d_in[7];
    const float* uo = (const float*)d_in[8];
    const float* gm = (const float*)d_in[9];
    unsigned short* wsu = (unsigned short*)d_ws;
    float* out = (float*)d_out;

    sn4<<<4, 256, 0, stream>>>(wt, wp, wg, wo, ut, up, ug, uo, wsu);
    convpool_mfma<<<512, 256, 0, stream>>>(x, wsu + U_WN,
                                           wsu + U_TH, wsu + U_PHI, wsu + U_G);
    attn_mfma<<<1024, 256, 0, stream>>>(wsu + U_TH, wsu + U_PHI, wsu + U_G, wsu + U_OT);
    outconv_mfma<<<1024, 256, 0, stream>>>(wsu + U_OT, wsu + U_WO, x, gm, out);
}

// Round 7
// 176.030 us; speedup vs baseline: 1.0961x; 1.0961x over previous
//
#include <hip/hip_runtime.h>
#include <hip/hip_bf16.h>

// SAGAN self-attention, B=16, C=128, H=W=64. Inputs fp32, output fp32.
// ws layout in ushorts (bf16):
//   U_WN  = 0        : Wn bf16 [96][128] (theta 0..15, phi 16..31, g 32..95)
//   U_WO  = 12288    : Wo bf16 [128][64]
//   U_TH  = 20480    : thetaT bf16 [16 b][4096 s][16 c]
//   U_PHI = 1069056  : phiT   bf16 [16 b][1024 t][16 c]
//   U_G   = 1331200  : gP     bf16 [16 b][64 c][1024 t'] (t-interleaved, see below)
//   U_OT  = 2379776  : oT     bf16 [16 b][4096 s][64 c]
//
// gP permutation: within each 64-t chunk, short index i maps to
// t = (i even) ? i/2 : i/2 + 32.  This matches the P-stash dword packing in
// attn (lane m packs {exp(S)[t=m], exp(S)[t=m+32]} into one dword), so PV's
// A (from LDS) and B (from gP) use the identical k->t order.

#define U_WN  0
#define U_WO  12288
#define U_TH  20480
#define U_PHI 1069056
#define U_G   1331200
#define U_OT  2379776

typedef __attribute__((ext_vector_type(8)))  short bf16x8;
typedef __attribute__((ext_vector_type(4)))  short s16x4;
typedef __attribute__((ext_vector_type(4)))  float f32x4;
typedef __attribute__((ext_vector_type(16))) float f32x16;

__device__ inline unsigned short f2b(float f) {
    union { float f; unsigned u; } v; v.f = f;
    unsigned r = v.u + 0x7FFFu + ((v.u >> 16) & 1u);   // RNE
    return (unsigned short)(r >> 16);
}
__device__ inline unsigned fbits(float f) {
    union { float f; unsigned u; } v; v.f = f; return v.u;
}
__device__ inline float b2f(unsigned short u) {
    union { unsigned u; float f; } v; v.u = ((unsigned)u) << 16; return v.f;
}

// ---------------- Kernel A: spectral norm, emit bf16 weights ----------------
__global__ __launch_bounds__(256) void sn4(
        const float* __restrict__ w0, const float* __restrict__ w1,
        const float* __restrict__ w2, const float* __restrict__ w3,
        const float* __restrict__ u0, const float* __restrict__ u1,
        const float* __restrict__ u2, const float* __restrict__ u3,
        unsigned short* __restrict__ wsu) {
    int wi = blockIdx.x;
    const float* W; const float* u; unsigned short* dst; int on, in_;
    if      (wi == 0) { W = w0; u = u0; dst = wsu;          on = 16;  in_ = 128; }
    else if (wi == 1) { W = w1; u = u1; dst = wsu + 2048;   on = 16;  in_ = 128; }
    else if (wi == 2) { W = w2; u = u2; dst = wsu + 4096;   on = 64;  in_ = 128; }
    else              { W = w3; u = u3; dst = wsu + 12288;  on = 128; in_ = 64;  }
    __shared__ float Wl[8320];    // [on][in_+1]
    __shared__ float ul[128];
    __shared__ float v[128];
    __shared__ float red[256];
    __shared__ float s_inv;
    int tid = threadIdx.x;
    int n = on * in_;
    int stride = in_ + 1;
    int shift = (in_ == 128) ? 7 : 6;
    int mask = in_ - 1;
    for (int i = tid; i < n; i += 256) {
        int o = i >> shift, j = i & mask;
        Wl[o * stride + j] = W[i];
    }
    if (tid < on) ul[tid] = u[tid];
    __syncthreads();
    float vi = 0.f;
    if (tid < in_) {
        for (int o = 0; o < on; ++o) vi += ul[o] * Wl[o * stride + tid];
    }
    red[tid] = (tid < in_) ? vi * vi : 0.f;
    __syncthreads();
    for (int st = 128; st > 0; st >>= 1) {
        if (tid < st) red[tid] += red[tid + st];
        __syncthreads();
    }
    float inv_nv = 1.0f / fmaxf(sqrtf(red[0]), 1e-12f);
    __syncthreads();
    if (tid < in_) v[tid] = vi * inv_nv;
    __syncthreads();
    float ui = 0.f;
    if (tid < on) {
        for (int i = 0; i < in_; ++i) ui += v[i] * Wl[tid * stride + i];
    }
    red[tid] = (tid < on) ? ui * ui : 0.f;
    __syncthreads();
    for (int st = 128; st > 0; st >>= 1) {
        if (tid < st) red[tid] += red[tid + st];
        __syncthreads();
    }
    if (tid == 0) {
        float nsq = red[0];
        float sv = nsq / fmaxf(sqrtf(nsq), 1e-12f);
        s_inv = 1.0f / sv;
    }
    __syncthreads();
    float inv = s_inv;
    for (int e = tid; e < n; e += 256) {
        int o = e >> shift, j = e & mask;
        dst[e] = f2b(Wl[o * stride + j] * inv);
    }
}

// ------- Kernel B: MFMA conv + 2x2 maxpool (g written t-permuted) -----------
__global__ __launch_bounds__(256) void convpool_mfma(
        const float* __restrict__ x, const unsigned short* __restrict__ wn,
        unsigned short* __restrict__ thetaT, unsigned short* __restrict__ phiT,
        unsigned short* __restrict__ gP) {
    __shared__ unsigned short smem[128 * 136];   // xT [px][c] s136; later poolbuf [80][132]
    int tid = threadIdx.x;
    int bb = blockIdx.x >> 5, tile = blockIdx.x & 31;
    int px0 = tile << 7;
    const float4* x4 = (const float4*)x;
    {
        int p4 = tid & 31, cg = (tid >> 5) * 4;
        for (int k = 0; k < 4; ++k) {
            int cb = k * 32 + cg;
            float4 v0 = x4[(bb * 128 + cb + 0) * 1024 + tile * 32 + p4];
            float4 v1 = x4[(bb * 128 + cb + 1) * 1024 + tile * 32 + p4];
            float4 v2 = x4[(bb * 128 + cb + 2) * 1024 + tile * 32 + p4];
            float4 v3 = x4[(bb * 128 + cb + 3) * 1024 + tile * 32 + p4];
            float a0[4] = {v0.x, v0.y, v0.z, v0.w};
            float a1[4] = {v1.x, v1.y, v1.z, v1.w};
            float a2[4] = {v2.x, v2.y, v2.z, v2.w};
            float a3[4] = {v3.x, v3.y, v3.z, v3.w};
#pragma unroll
            for (int j = 0; j < 4; ++j) {
                s16x4 u; u[0] = (short)f2b(a0[j]); u[1] = (short)f2b(a1[j]);
                u[2] = (short)f2b(a2[j]); u[3] = (short)f2b(a3[j]);
                *(s16x4*)&smem[(p4 * 4 + j) * 136 + cb] = u;
            }
        }
    }
    __syncthreads();
    int lane = tid & 63, wv = tid >> 6;
    int q = lane >> 4, l = lane & 15;
    int pxw = wv * 32;
    f32x4 acc[2][6];
    const f32x4 z4 = {0.f, 0.f, 0.f, 0.f};
#pragma unroll
    for (int mt = 0; mt < 2; ++mt)
#pragma unroll
        for (int nt = 0; nt < 6; ++nt) acc[mt][nt] = z4;
#pragma unroll
    for (int kk = 0; kk < 4; ++kk) {
        bf16x8 a0 = *(const bf16x8*)&smem[(pxw + l) * 136 + kk * 32 + q * 8];
        bf16x8 a1 = *(const bf16x8*)&smem[(pxw + 16 + l) * 136 + kk * 32 + q * 8];
#pragma unroll
        for (int nt = 0; nt < 6; ++nt) {
            bf16x8 bw = *(const bf16x8*)&wn[(nt * 16 + l) * 128 + kk * 32 + q * 8];
            acc[0][nt] = __builtin_amdgcn_mfma_f32_16x16x32_bf16(a0, bw, acc[0][nt], 0, 0, 0);
            acc[1][nt] = __builtin_amdgcn_mfma_f32_16x16x32_bf16(a1, bw, acc[1][nt], 0, 0, 0);
        }
    }
#pragma unroll
    for (int mt = 0; mt < 2; ++mt)
#pragma unroll
        for (int r = 0; r < 4; ++r) {
            int s = px0 + pxw + mt * 16 + q * 4 + r;
            thetaT[(bb * 4096 + s) * 16 + l] = f2b(acc[mt][0][r]);
        }
    __syncthreads();
    unsigned short* poolbuf = smem;   // [80 ch][px] stride 132
#pragma unroll
    for (int mt = 0; mt < 2; ++mt)
#pragma unroll
        for (int nt = 1; nt < 6; ++nt) {
            int ch = nt * 16 + l - 16;
#pragma unroll
            for (int r = 0; r < 4; ++r) {
                poolbuf[ch * 132 + pxw + mt * 16 + q * 4 + r] = f2b(acc[mt][nt][r]);
            }
        }
    __syncthreads();
    for (int i = tid; i < 2560; i += 256) {
        int tcol = i & 31, ch = i >> 5;
        int base = ch * 132 + tcol * 2;
        float m0 = fmaxf(b2f(poolbuf[base]), b2f(poolbuf[base + 1]));
        float m1 = fmaxf(b2f(poolbuf[base + 64]), b2f(poolbuf[base + 65]));
        float m = fmaxf(m0, m1);
        int t = tile * 32 + tcol;
        if (ch < 16) phiT[(bb * 1024 + t) * 16 + ch] = f2b(m);
        else {
            // permuted g: within 64-chunk, t -> 2*(t&31) + ((t>>5)&1)
            int tp = (t & ~63) + ((t & 31) << 1) + ((t >> 5) & 1);
            gP[(bb * 64 + ch - 16) * 1024 + tp] = f2b(m);
        }
    }
}

// ------- Kernel C: MFMA fused attention v4 ----------------------------------
// grid: 16 b x 64 s-tiles (64 s) = 1024 blocks, 4 waves.
// Wave (pair, half): pair = 32-s subtile, half = 512-t range (8 chunks).
// 32x32x16 mfma, exact K=16 for S. Single psT/wave (18.4 KB total LDS).
// P stashed as interleaved dwords (16 ds_write_b32/chunk); g B-frags loaded
// at chunk top (hoisted off PV critical path); phi frags prefetched.
__global__ __launch_bounds__(256) void attn_mfma(
        const unsigned short* __restrict__ thetaT,
        const unsigned short* __restrict__ phiT,
        const unsigned short* __restrict__ gP,
        unsigned short* __restrict__ oT) {
    __shared__ unsigned int lds4[4608];   // 4 psT regions [32 s][36 dw]; comb overlay
    int tid = threadIdx.x;
    int bb = blockIdx.x >> 6, st = blockIdx.x & 63;
    int s0 = st << 6;
    int lane = tid & 63, wv = tid >> 6;
    int m = lane & 31, h = lane >> 5;
    int pair = wv >> 1, half = wv & 1;
    int sW = s0 + pair * 32;
    const f32x16 z16 = {0.f,0.f,0.f,0.f,0.f,0.f,0.f,0.f,0.f,0.f,0.f,0.f,0.f,0.f,0.f,0.f};

    bf16x8 a_th = *(const bf16x8*)&thetaT[(bb * 4096 + sW + m) * 16 + h * 8];

    f32x16 acc[2];
    acc[0] = z16; acc[1] = z16;
    float lp[16];
#pragma unroll
    for (int r = 0; r < 16; ++r) lp[r] = 0.f;

    const unsigned short* phB = &phiT[bb * 16384];
    const unsigned short* gB  = &gP[bb * 65536];
    int tbase = half * 512;
    unsigned int* ps = &lds4[wv * 1152];          // wave-private [32 s][36 dw]
    unsigned short* pss = (unsigned short*)ps;

    bf16x8 bp[2], bpn[2];
#pragma unroll
    for (int tg = 0; tg < 2; ++tg)
        bp[tg] = *(const bf16x8*)&phB[(tbase + tg * 32 + m) * 16 + h * 8];

#pragma unroll
    for (int i = 0; i < 8; ++i) {
        int t0 = tbase + (i << 6);
        // hoist all g B-frags for this chunk (independent of S/exp below)
        bf16x8 bg[4][2];
#pragma unroll
        for (int kt = 0; kt < 4; ++kt)
#pragma unroll
            for (int cg = 0; cg < 2; ++cg)
                bg[kt][cg] = *(const bf16x8*)&gB[(cg * 32 + m) * 1024 + t0 + kt * 16 + h * 8];
        if (i < 7) {
#pragma unroll
            for (int tg = 0; tg < 2; ++tg)
                bpn[tg] = *(const bf16x8*)&phB[(t0 + 64 + tg * 32 + m) * 16 + h * 8];
        }
        // S = theta^T phi : 32 s x 64 t
        f32x16 sacc0 = __builtin_amdgcn_mfma_f32_32x32x16_bf16(a_th, bp[0], z16, 0, 0, 0);
        f32x16 sacc1 = __builtin_amdgcn_mfma_f32_32x32x16_bf16(a_th, bp[1], z16, 0, 0, 0);
        // P = exp(S), packed dword stash: lane m -> {t=t0+m, t=t0+32+m}
#pragma unroll
        for (int r = 0; r < 16; ++r) {
            int row = (r & 3) + 8 * (r >> 2) + 4 * h;
            float e0 = __expf(sacc0[r]);
            float e1 = __expf(sacc1[r]);
            lp[r] += e0 + e1;
            unsigned u = (fbits(e0) >> 16) | (fbits(e1) & 0xFFFF0000u);
            ps[row * 36 + m] = u;
        }
        // PV: O^T[s][c] += P[s][t] g^T[t][c]  (k-order matches gP permutation)
#pragma unroll
        for (int kt = 0; kt < 4; ++kt) {
            bf16x8 ap = *(const bf16x8*)&pss[m * 72 + kt * 16 + h * 8];
#pragma unroll
            for (int cg = 0; cg < 2; ++cg)
                acc[cg] = __builtin_amdgcn_mfma_f32_32x32x16_bf16(ap, bg[kt][cg], acc[cg], 0, 0, 0);
        }
        bp[0] = bpn[0]; bp[1] = bpn[1];
    }
    // partial row sums over this wave's 512 t
    float lsum[16];
#pragma unroll
    for (int r = 0; r < 16; ++r) {
        float v = lp[r];
        v += __shfl_xor(v, 1);
        v += __shfl_xor(v, 2);
        v += __shfl_xor(v, 4);
        v += __shfl_xor(v, 8);
        v += __shfl_xor(v, 16);
        lsum[r] = v;
    }
    // combine the two t-halves of each pair via LDS overlay
    __syncthreads();
    float* comb = (float*)lds4;              // [2 pairs][32 s][64 c] = 16 KB
    float* Lb = (float*)&lds4[4096];         // [2 pairs][32 s]
    if (half == 1) {
#pragma unroll
        for (int cg = 0; cg < 2; ++cg)
#pragma unroll
            for (int r = 0; r < 16; ++r) {
                int row = (r & 3) + 8 * (r >> 2) + 4 * h;
                comb[pair * 2048 + row * 64 + cg * 32 + m] = acc[cg][r];
            }
        if (m == 0) {
#pragma unroll
            for (int r = 0; r < 16; ++r) {
                int row = (r & 3) + 8 * (r >> 2) + 4 * h;
                Lb[pair * 32 + row] = lsum[r];
            }
        }
    }
    __syncthreads();
    if (half == 0) {
#pragma unroll
        for (int r = 0; r < 16; ++r) {
            int row = (r & 3) + 8 * (r >> 2) + 4 * h;
            float inv = 1.0f / (lsum[r] + Lb[pair * 32 + row]);
#pragma unroll
            for (int cg = 0; cg < 2; ++cg) {
                float v = acc[cg][r] + comb[pair * 2048 + row * 64 + cg * 32 + m];
                oT[(bb * 4096 + sW + row) * 64 + cg * 32 + m] = f2b(v * inv);
            }
        }
    }
}

// ------- Kernel D: out = gamma * (Wo @ o) + x  (unchanged) ------------------
__global__ __launch_bounds__(256) void outconv_mfma(
        const unsigned short* __restrict__ oT, const unsigned short* __restrict__ wo,
        const float* __restrict__ x, const float* __restrict__ gam,
        float* __restrict__ out) {
    int tid = threadIdx.x;
    int bb = blockIdx.x >> 6, tile = blockIdx.x & 63;
    int lane = tid & 63, wv = tid >> 6;
    int q = lane >> 4, l = lane & 15;
    int pxw = tile * 64 + wv * 16;
    bf16x8 af[2];
#pragma unroll
    for (int kk = 0; kk < 2; ++kk)
        af[kk] = *(const bf16x8*)&oT[(bb * 4096 + pxw + l) * 64 + kk * 32 + q * 8];
    f32x4 acc[8];
    const f32x4 z4 = {0.f, 0.f, 0.f, 0.f};
#pragma unroll
    for (int nt = 0; nt < 8; ++nt) acc[nt] = z4;
#pragma unroll
    for (int kk = 0; kk < 2; ++kk)
#pragma unroll
        for (int nt = 0; nt < 8; ++nt) {
            bf16x8 bw = *(const bf16x8*)&wo[(nt * 16 + l) * 64 + kk * 32 + q * 8];
            acc[nt] = __builtin_amdgcn_mfma_f32_16x16x32_bf16(af[kk], bw, acc[nt], 0, 0, 0);
        }
    float gm = gam[0];
    const float4* x4 = (const float4*)x;
    float4* out4 = (float4*)out;
#pragma unroll
    for (int nt = 0; nt < 8; ++nt) {
        int oc = nt * 16 + l;
        int gi = (bb * 128 + oc) * 1024 + (pxw >> 2) + q;
        float4 xv = x4[gi];
        float4 r;
        r.x = gm * acc[nt][0] + xv.x;
        r.y = gm * acc[nt][1] + xv.y;
        r.z = gm * acc[nt][2] + xv.z;
        r.w = gm * acc[nt][3] + xv.w;
        out4[gi] = r;
    }
}

extern "C" void kernel_launch(void* const* d_in, const int* in_sizes, int n_in,
                              void* d_out, int out_size, void* d_ws, size_t ws_size,
                              hipStream_t stream) {
    const float* x  = (const float*)d_in[0];
    const float* wt = (const float*)d_in[1];
    const float* wp = (const float*)d_in[2];
    const float* wg = (const float*)d_in[3];
    const float* wo = (const float*)d_in[4];
    const float* ut = (const float*)d_in[5];
    const float* up = (const float*)d_in[6];
    const float* ug = (const float*)d_in[7];
    const float* uo = (const float*)d_in[8];
    const float* gm = (const float*)d_in[9];
    unsigned short* wsu = (unsigned short*)d_ws;
    float* out = (float*)d_out;

    sn4<<<4, 256, 0, stream>>>(wt, wp, wg, wo, ut, up, ug, uo, wsu);
    convpool_mfma<<<512, 256, 0, stream>>>(x, wsu + U_WN,
                                           wsu + U_TH, wsu + U_PHI, wsu + U_G);
    attn_mfma<<<1024, 256, 0, stream>>>(wsu + U_TH, wsu + U_PHI, wsu + U_G, wsu + U_OT);
    outconv_mfma<<<1024, 256, 0, stream>>>(wsu + U_OT, wsu + U_WO, x, gm, out);
}